// Round 10
// baseline (255.566 us; speedup 1.0000x reference)
//
#include <hip/hip_runtime.h>
#include <hip/hip_fp16.h>
#include <math.h>

#define CC 64
#define KK 16
#define NNODES 15
#define DD 512      // input feature dim
#define MM 512      // output dim
#define NN 16384    // rows

// ---------------------------------------------------------------------------
// XLA/Eigen fast-tanh for f32 (bit-exact vs JAX's jnp.tanh lowering).
// Round 3/4/5 evidence: required to match the golden's argmax codes.
// ---------------------------------------------------------------------------
__device__ __forceinline__ float xla_tanhf(float x) {
    const float kMax = 7.90531110763549805f;
    bool tiny = fabsf(x) < 0.0004f;
    float xc = fminf(fmaxf(x, -kMax), kMax);
    float x2 = __fmul_rn(xc, xc);
    float p = __fmaf_rn(x2, -2.76076847742355e-16f, 2.00018790482477e-13f);
    p = __fmaf_rn(x2, p, -8.60467152213735e-11f);
    p = __fmaf_rn(x2, p, 5.12229709037114e-08f);
    p = __fmaf_rn(x2, p, 1.48572235717979e-05f);
    p = __fmaf_rn(x2, p, 6.37261928875436e-04f);
    p = __fmaf_rn(x2, p, 4.89352455891786e-03f);
    p = __fmul_rn(xc, p);
    float q = __fmaf_rn(x2, 1.19825839466702e-06f, 1.18534705686654e-04f);
    q = __fmaf_rn(x2, q, 2.26843463243900e-03f);
    q = __fmaf_rn(x2, q, 4.89352518554385e-03f);
    return tiny ? x : __fdiv_rn(p, q);
}

// ---------------------------------------------------------------------------
// Kernel 1: transpose — L (M, C*K) fp32 -> Lt16 (C*K, M) fp16 via LDS
// 64x64 tiles: coalesced reads AND coalesced 16B writes. (round-7 verified)
// ---------------------------------------------------------------------------
__global__ __launch_bounds__(256) void transpose_lut16(const float* __restrict__ L,
                                                       __half* __restrict__ Lt) {
    __shared__ __half tile[64 * 72];   // [ck_local][m_local], stride 72
    const int tid = threadIdx.x;
    const int ck0 = (blockIdx.x & 15) * 64;
    const int m0  = (blockIdx.x >> 4) * 64;

    const int col = tid & 63;
#pragma unroll
    for (int i = 0; i < 16; ++i) {
        int r = (tid >> 6) + i * 4;
        float v = L[(size_t)(m0 + r) * (CC * KK) + ck0 + col];
        tile[col * 72 + r] = __float2half(v);
    }
    __syncthreads();

#pragma unroll
    for (int t = 0; t < 2; ++t) {
        int cr   = (tid >> 3) + t * 32;
        int mseg = (tid & 7) * 8;
        uint4 v = *(const uint4*)&tile[cr * 72 + mseg];
        *(uint4*)(Lt + ((size_t)(ck0 + cr) * MM + m0 + mseg)) = v;
    }
}

// ---------------------------------------------------------------------------
// Kernel 2: FUSED encode+decode v3.
// Round-9 lesson: keep VGPR low (occupancy 66%->20% killed round 9).
// This version:
//  - encode: transposed sA/sT (bank-conflict-free, round-9 verified; codes
//    bit-exact since round 5).
//  - decode: k is wave-uniform -> readfirstlane to SGPR; address math is
//    SALU (free, overlaps VALU); loads are saddr-form dwordx4.
//  - accumulate with v_pk_add_f16 (4 instr/c instead of 16), 8 accumulator
//    sets of 8 c's each to bound fp16 rounding (~0.1-0.25 extra, budget 0.835).
//  - codes stay in LDS (broadcast reads), partial unroll, launch_bounds cap.
// ---------------------------------------------------------------------------
__global__ __launch_bounds__(256, 6) void fused_kernel(const float* __restrict__ I,
                                                       const float* __restrict__ A,
                                                       const float* __restrict__ T,
                                                       const __half* __restrict__ Lt,
                                                       float* __restrict__ out) {
    __shared__ float sAT[32 * 64];     // [s*4+d][c]  (transposed, conflict-free)
    __shared__ float sTT[NNODES * 64]; // [i][c]      (transposed, conflict-free)
    __shared__ unsigned int sIdxW[4 * 16];  // 4 rows x 16 code-words

    const int tid = threadIdx.x;
    for (int g = tid; g < 32 * 64; g += 256)      // sAT[sd*64+c] = A[c*32+sd]
        sAT[g] = A[((g & 63) << 5) + (g >> 6)];
    for (int g = tid; g < NNODES * 64; g += 256)  // sTT[i*64+c] = T[c*15+i]
        sTT[g] = T[(g & 63) * NNODES + (g >> 6)];
    __syncthreads();

    const int w    = tid >> 6;        // wave = local row
    const int lane = tid & 63;
    const int c    = lane;            // encode subspace
    const int j    = blockIdx.x * 4 + w;

    // ---------------- encode (bit-exact round-5 math) ----------------
    {
        const float* Ij = I + (size_t)j * DD + c * 8;   // wave reads 2KB contiguous
        float4 v0 = ((const float4*)Ij)[0];
        float4 v1 = ((const float4*)Ij)[1];
        float iv[8] = {v0.x, v0.y, v0.z, v0.w, v1.x, v1.y, v1.z, v1.w};

        float t[4] = {0.f, 0.f, 0.f, 0.f};
#pragma unroll
        for (int s = 0; s < 8; ++s) {
            float v = iv[s];
#pragma unroll
            for (int d = 0; d < 4; ++d)
                t[d] = __fmaf_rn(v, sAT[(s * 4 + d) * 64 + c], t[d]);
        }

        const int lvl[NNODES] = {0, 1, 1, 2, 2, 2, 2, 3, 3, 3, 3, 3, 3, 3, 3};
        float th[NNODES];
#pragma unroll
        for (int i = 0; i < NNODES; ++i) {
            float h = __fsub_rn(t[lvl[i]], sTT[i * 64 + c]);
            th[i] = xla_tanhf(h);
        }

        int best = 0;
        float bestv = -3.0e38f;
#pragma unroll
        for (int k = 0; k < KK; ++k) {
            int node = 0;
            float s = 0.f;
#pragma unroll
            for (int l = 0; l < 4; ++l) {
                int bit = (k >> (3 - l)) & 1;
                s = __fadd_rn(s, bit ? th[node] : -th[node]);
                node = 2 * node + 1 + bit;
            }
            if (s > bestv) { bestv = s; best = k; }   // strict >: first-max
        }
        ((unsigned char*)sIdxW)[w * CC + lane] = (unsigned char)best;
    }
    __syncthreads();

    // ---------------- decode: scalar-addressed, pk_add_f16 ----------------
    const int m0 = lane * 8;          // 8 consecutive m per lane
    const unsigned int* codeWords = &sIdxW[w * 16];

    __half2 acc[8][4];                // 8 sets x 4 half2 (8 m) = 32 VGPRs
#pragma unroll
    for (int s = 0; s < 8; ++s)
#pragma unroll
        for (int q = 0; q < 4; ++q) acc[s][q] = __half2half2(__ushort_as_half(0));

#pragma unroll 4
    for (int g = 0; g < 16; ++g) {    // word g covers c = 4g..4g+3
        unsigned int word = (unsigned int)__builtin_amdgcn_readfirstlane((int)codeWords[g]);
        const int s = g & 7;
        const int c0 = g * 4;
        // scalar row offsets -> saddr-form loads; lane contributes m0 voffset
        const uint4 v0 = *(const uint4*)(Lt + (((c0 + 0) * 16 + (int)( word        & 0xffu)) << 9) + m0);
        const uint4 v1 = *(const uint4*)(Lt + (((c0 + 1) * 16 + (int)((word >>  8) & 0xffu)) << 9) + m0);
        const uint4 v2 = *(const uint4*)(Lt + (((c0 + 2) * 16 + (int)((word >> 16) & 0xffu)) << 9) + m0);
        const uint4 v3 = *(const uint4*)(Lt + (((c0 + 3) * 16 + (int)( word >> 24        )) << 9) + m0);

        const unsigned int u0[4] = {v0.x, v0.y, v0.z, v0.w};
        const unsigned int u1[4] = {v1.x, v1.y, v1.z, v1.w};
        const unsigned int u2[4] = {v2.x, v2.y, v2.z, v2.w};
        const unsigned int u3[4] = {v3.x, v3.y, v3.z, v3.w};
#pragma unroll
        for (int q = 0; q < 4; ++q) {
            acc[s][q] = __hadd2(acc[s][q], *(const __half2*)&u0[q]);
            acc[s][q] = __hadd2(acc[s][q], *(const __half2*)&u1[q]);
            acc[s][q] = __hadd2(acc[s][q], *(const __half2*)&u2[q]);
            acc[s][q] = __hadd2(acc[s][q], *(const __half2*)&u3[q]);
        }
    }

    // final: convert 8 fp16 partials per m to fp32 and sum
    float f[8];
#pragma unroll
    for (int q = 0; q < 4; ++q) {
        float sx = 0.f, sy = 0.f;
#pragma unroll
        for (int s = 0; s < 8; ++s) {
            float2 v = __half22float2(acc[s][q]);
            sx = __fadd_rn(sx, v.x);
            sy = __fadd_rn(sy, v.y);
        }
        f[2 * q] = sx; f[2 * q + 1] = sy;
    }

    float* o = out + (size_t)j * MM + m0;
    *(float4*)(o)     = make_float4(f[0], f[1], f[2], f[3]);
    *(float4*)(o + 4) = make_float4(f[4], f[5], f[6], f[7]);
}

// ---------------------------------------------------------------------------
extern "C" void kernel_launch(void* const* d_in, const int* in_sizes, int n_in,
                              void* d_out, int out_size, void* d_ws, size_t ws_size,
                              hipStream_t stream) {
    const float* I = (const float*)d_in[0];  // (N, D) fp32
    const float* A = (const float*)d_in[1];  // (C, 8, 4) fp32
    const float* T = (const float*)d_in[2];  // (C*15,) fp32
    const float* L = (const float*)d_in[3];  // (M, C, K) fp32
    // d_in[4] = S, d_in[5] = B: structural constants, hard-coded.

    __half* Lt16 = (__half*)d_ws;            // 1 MB fp16 LUT
    float* out = (float*)d_out;              // (N, M) fp32

    hipLaunchKernelGGL(transpose_lut16, dim3(128), dim3(256), 0, stream, L, Lt16);
    hipLaunchKernelGGL(fused_kernel, dim3(NN / 4), dim3(256), 0, stream, I, A, T, Lt16, out);
}

// Round 11
// 140.236 us; speedup vs baseline: 1.8224x; 1.8224x over previous
//
#include <hip/hip_runtime.h>
#include <hip/hip_fp16.h>
#include <math.h>

#define CC 64
#define KK 16
#define NNODES 15
#define DD 512      // input feature dim
#define MM 512      // output dim
#define NN 16384    // rows

// ---------------------------------------------------------------------------
// XLA/Eigen fast-tanh for f32 (bit-exact vs JAX's jnp.tanh lowering).
// Round 3/4/5 evidence: required to match the golden's argmax codes.
// ---------------------------------------------------------------------------
__device__ __forceinline__ float xla_tanhf(float x) {
    const float kMax = 7.90531110763549805f;
    bool tiny = fabsf(x) < 0.0004f;
    float xc = fminf(fmaxf(x, -kMax), kMax);
    float x2 = __fmul_rn(xc, xc);
    float p = __fmaf_rn(x2, -2.76076847742355e-16f, 2.00018790482477e-13f);
    p = __fmaf_rn(x2, p, -8.60467152213735e-11f);
    p = __fmaf_rn(x2, p, 5.12229709037114e-08f);
    p = __fmaf_rn(x2, p, 1.48572235717979e-05f);
    p = __fmaf_rn(x2, p, 6.37261928875436e-04f);
    p = __fmaf_rn(x2, p, 4.89352455891786e-03f);
    p = __fmul_rn(xc, p);
    float q = __fmaf_rn(x2, 1.19825839466702e-06f, 1.18534705686654e-04f);
    q = __fmaf_rn(x2, q, 2.26843463243900e-03f);
    q = __fmaf_rn(x2, q, 4.89352518554385e-03f);
    return tiny ? x : __fdiv_rn(p, q);
}

// ---------------------------------------------------------------------------
// Kernel 1: transpose — L (M, C*K) fp32 -> Lt16 (C*K, M) fp16 via LDS
// 64x64 tiles: coalesced reads AND coalesced 16B writes. (round-7 verified)
// ---------------------------------------------------------------------------
__global__ __launch_bounds__(256) void transpose_lut16(const float* __restrict__ L,
                                                       __half* __restrict__ Lt) {
    __shared__ __half tile[64 * 72];   // [ck_local][m_local], stride 72
    const int tid = threadIdx.x;
    const int ck0 = (blockIdx.x & 15) * 64;
    const int m0  = (blockIdx.x >> 4) * 64;

    const int col = tid & 63;
#pragma unroll
    for (int i = 0; i < 16; ++i) {
        int r = (tid >> 6) + i * 4;
        float v = L[(size_t)(m0 + r) * (CC * KK) + ck0 + col];
        tile[col * 72 + r] = __float2half(v);
    }
    __syncthreads();

#pragma unroll
    for (int t = 0; t < 2; ++t) {
        int cr   = (tid >> 3) + t * 32;
        int mseg = (tid & 7) * 8;
        uint4 v = *(const uint4*)&tile[cr * 72 + mseg];
        *(uint4*)(Lt + ((size_t)(ck0 + cr) * MM + m0 + mseg)) = v;
    }
}

// ---------------------------------------------------------------------------
// Kernel 2: FUSED encode+decode v4.
// Lessons baked in:
//  r8: conflicted sA cost 3.67M LDS stall-cycles -> transposed layouts (r9: 0).
//  r9: unconstrained full-unroll hoisting -> VGPR 100, occupancy 20%. Cap it.
//  r10: partial unroll + dynamic acc index -> SCRATCH SPILL (400MB writes).
//       => FULL unroll, CONSTANT-indexed acc, __launch_bounds__(256,6).
// Decode: wave-uniform code word via readfirstlane (SALU addresses, saddr
// loads), 4 fp16 pk_add accumulator chains (16 adds each; err ~0.04 vs 0.59
// budget), fp32 final combine.
// ---------------------------------------------------------------------------
__global__ __launch_bounds__(256, 6) void fused_kernel(const float* __restrict__ I,
                                                       const float* __restrict__ A,
                                                       const float* __restrict__ T,
                                                       const __half* __restrict__ Lt,
                                                       float* __restrict__ out) {
    __shared__ float sAT[32 * 64];     // [s*4+d][c]  (transposed, conflict-free)
    __shared__ float sTT[NNODES * 64]; // [i][c]      (transposed, conflict-free)
    __shared__ unsigned int sIdxW[4 * 16];  // 4 rows x 16 code-words

    const int tid = threadIdx.x;
    for (int g = tid; g < 32 * 64; g += 256)      // sAT[sd*64+c] = A[c*32+sd]
        sAT[g] = A[((g & 63) << 5) + (g >> 6)];
    for (int g = tid; g < NNODES * 64; g += 256)  // sTT[i*64+c] = T[c*15+i]
        sTT[g] = T[(g & 63) * NNODES + (g >> 6)];
    __syncthreads();

    const int w    = tid >> 6;        // wave = local row
    const int lane = tid & 63;
    const int c    = lane;            // encode subspace
    const int j    = blockIdx.x * 4 + w;

    // ---------------- encode (bit-exact round-5 math) ----------------
    {
        const float* Ij = I + (size_t)j * DD + c * 8;   // wave reads 2KB contiguous
        float4 v0 = ((const float4*)Ij)[0];
        float4 v1 = ((const float4*)Ij)[1];
        float iv[8] = {v0.x, v0.y, v0.z, v0.w, v1.x, v1.y, v1.z, v1.w};

        float t[4] = {0.f, 0.f, 0.f, 0.f};
#pragma unroll
        for (int s = 0; s < 8; ++s) {
            float v = iv[s];
#pragma unroll
            for (int d = 0; d < 4; ++d)
                t[d] = __fmaf_rn(v, sAT[(s * 4 + d) * 64 + c], t[d]);
        }

        const int lvl[NNODES] = {0, 1, 1, 2, 2, 2, 2, 3, 3, 3, 3, 3, 3, 3, 3};
        float th[NNODES];
#pragma unroll
        for (int i = 0; i < NNODES; ++i) {
            float h = __fsub_rn(t[lvl[i]], sTT[i * 64 + c]);
            th[i] = xla_tanhf(h);
        }

        int best = 0;
        float bestv = -3.0e38f;
#pragma unroll
        for (int k = 0; k < KK; ++k) {
            int node = 0;
            float s = 0.f;
#pragma unroll
            for (int l = 0; l < 4; ++l) {
                int bit = (k >> (3 - l)) & 1;
                s = __fadd_rn(s, bit ? th[node] : -th[node]);
                node = 2 * node + 1 + bit;
            }
            if (s > bestv) { bestv = s; best = k; }   // strict >: first-max
        }
        ((unsigned char*)sIdxW)[w * CC + lane] = (unsigned char)best;
    }
    __syncthreads();

    // ---------------- decode: SALU addresses + fp16 pk_add ----------------
    const int m0 = lane * 8;          // 8 consecutive m per lane
    const unsigned int* codeWords = &sIdxW[w * 16];
    const __half* lt = Lt + m0;

    // 4 accumulator sets x 4 half2; constant indices only (fully unrolled).
    __half2 acc[4][4];
#pragma unroll
    for (int s = 0; s < 4; ++s)
#pragma unroll
        for (int q = 0; q < 4; ++q) acc[s][q] = __half2half2(__ushort_as_half(0));

#pragma unroll
    for (int g = 0; g < 16; ++g) {    // FULL unroll: g compile-time constant
        unsigned int word = (unsigned int)__builtin_amdgcn_readfirstlane((int)codeWords[g]);
        // load x of this group -> accumulator set x (4 independent chains)
        const uint4 v0 = *(const uint4*)(lt + (((g * 4 + 0) * 16 + (int)( word        & 0xffu)) << 9));
        const uint4 v1 = *(const uint4*)(lt + (((g * 4 + 1) * 16 + (int)((word >>  8) & 0xffu)) << 9));
        const uint4 v2 = *(const uint4*)(lt + (((g * 4 + 2) * 16 + (int)((word >> 16) & 0xffu)) << 9));
        const uint4 v3 = *(const uint4*)(lt + (((g * 4 + 3) * 16 + (int)( word >> 24        )) << 9));

        const unsigned int u0[4] = {v0.x, v0.y, v0.z, v0.w};
        const unsigned int u1[4] = {v1.x, v1.y, v1.z, v1.w};
        const unsigned int u2[4] = {v2.x, v2.y, v2.z, v2.w};
        const unsigned int u3[4] = {v3.x, v3.y, v3.z, v3.w};
#pragma unroll
        for (int q = 0; q < 4; ++q) {
            acc[0][q] = __hadd2(acc[0][q], *(const __half2*)&u0[q]);
            acc[1][q] = __hadd2(acc[1][q], *(const __half2*)&u1[q]);
            acc[2][q] = __hadd2(acc[2][q], *(const __half2*)&u2[q]);
            acc[3][q] = __hadd2(acc[3][q], *(const __half2*)&u3[q]);
        }
    }

    // final: fp32 combine of the 4 fp16 partials per m
    float f[8];
#pragma unroll
    for (int q = 0; q < 4; ++q) {
        float2 p0 = __half22float2(acc[0][q]);
        float2 p1 = __half22float2(acc[1][q]);
        float2 p2 = __half22float2(acc[2][q]);
        float2 p3 = __half22float2(acc[3][q]);
        f[2 * q]     = __fadd_rn(__fadd_rn(p0.x, p1.x), __fadd_rn(p2.x, p3.x));
        f[2 * q + 1] = __fadd_rn(__fadd_rn(p0.y, p1.y), __fadd_rn(p2.y, p3.y));
    }

    float* o = out + (size_t)j * MM + m0;
    *(float4*)(o)     = make_float4(f[0], f[1], f[2], f[3]);
    *(float4*)(o + 4) = make_float4(f[4], f[5], f[6], f[7]);
}

// ---------------------------------------------------------------------------
extern "C" void kernel_launch(void* const* d_in, const int* in_sizes, int n_in,
                              void* d_out, int out_size, void* d_ws, size_t ws_size,
                              hipStream_t stream) {
    const float* I = (const float*)d_in[0];  // (N, D) fp32
    const float* A = (const float*)d_in[1];  // (C, 8, 4) fp32
    const float* T = (const float*)d_in[2];  // (C*15,) fp32
    const float* L = (const float*)d_in[3];  // (M, C, K) fp32
    // d_in[4] = S, d_in[5] = B: structural constants, hard-coded.

    __half* Lt16 = (__half*)d_ws;            // 1 MB fp16 LUT
    float* out = (float*)d_out;              // (N, M) fp32

    hipLaunchKernelGGL(transpose_lut16, dim3(128), dim3(256), 0, stream, L, Lt16);
    hipLaunchKernelGGL(fused_kernel, dim3(NN / 4), dim3(256), 0, stream, I, A, T, Lt16, out);
}